// Round 6
// baseline (759.436 us; speedup 1.0000x reference)
//
#include <hip/hip_runtime.h>
#include <cstdint>

// B=4, S=2048, H=512, NH=8, HD=64 — ONE plain launch, 4 phases, hand grid-barrier:
//   prep (cvt_w + cvt_x + mask_bits) | qkv (bf16 128x128, 768 jobs) |
//   attn (1024 jobs, r2 structure) | out_gemm (512 jobs)
// grid 1024x256, 32KB LDS, __launch_bounds__(256,4) => exactly 4 blk/CU x 256 CU
// co-residency; barrier = monotonic ticket counter zeroed via hipMemsetAsync.
// ws: Oh 0-8Mi | Qh 8-16 | Kh 16-24 | Vt 24-32 | MB 32-34 | Wb 34-36 | Xb 36-60 |
//     bar @ 60 MiB

typedef __bf16 bf16x8 __attribute__((ext_vector_type(8)));
typedef float  f32x4  __attribute__((ext_vector_type(4)));
typedef float  f32x16 __attribute__((ext_vector_type(16)));
typedef unsigned int uint32x2 __attribute__((ext_vector_type(2)));

#define MFMA16(a, b, c) __builtin_amdgcn_mfma_f32_16x16x32_bf16(a, b, c, 0, 0, 0)
#define MFMA32(a, b, c) __builtin_amdgcn_mfma_f32_32x32x16_bf16(a, b, c, 0, 0, 0)

__device__ __forceinline__ ushort f2bf(float f) {
  union { float f; uint32_t u; } v; v.f = f;
  return (ushort)((v.u + 0x8000u) >> 16);
}
__device__ __forceinline__ uint cvtpk(float a, float b) {
  uint r;
  asm("v_cvt_pk_bf16_f32 %0, %1, %2" : "=v"(r) : "v"(a), "v"(b));
  return r;
}
__device__ __forceinline__ float exp2r(float x) {
#if __has_builtin(__builtin_amdgcn_exp2f)
  return __builtin_amdgcn_exp2f(x);
#else
  return exp2f(x);
#endif
}

typedef const __attribute__((address_space(1))) unsigned int* gas_u32;
typedef __attribute__((address_space(3))) unsigned int* las_u32;
__device__ __forceinline__ void gll16(const void* g, void* l) {
  __builtin_amdgcn_global_load_lds((gas_u32)g, (las_u32)l, 16, 0, 0);
}

// grid barrier: monotonic ticket counter; each instance owns a 1024-ticket range.
__device__ __forceinline__ void gbar(unsigned* bar, int tid) {
  __syncthreads();                     // block's phase work complete
  if (tid == 0) {
    __threadfence();                   // release (agent scope: L2 writeback)
    unsigned old = atomicAdd(bar, 1u); // device-scope RMW
    unsigned target = (old / 1024u + 1u) * 1024u;
    while (__hip_atomic_load(bar, __ATOMIC_RELAXED, __HIP_MEMORY_SCOPE_AGENT) < target)
      __builtin_amdgcn_s_sleep(2);
  }
  __syncthreads();
  __threadfence();                     // acquire (invalidate stale lines)
}

// ---------------------------------------------------------------- megakernel
__global__ __launch_bounds__(256, 4) void mega(
    const float* __restrict__ q, const float* __restrict__ k,
    const float* __restrict__ v, const int* __restrict__ mask,
    const float* __restrict__ Wq, const float* __restrict__ bq,
    const float* __restrict__ Wk, const float* __restrict__ bk,
    const float* __restrict__ Wv, const float* __restrict__ bv,
    const float* __restrict__ Wo, const float* __restrict__ bo,
    float* __restrict__ out, ushort* __restrict__ Oh,
    ushort* __restrict__ Qh, ushort* __restrict__ Kh,
    ushort* __restrict__ Vt, unsigned long long* __restrict__ MB,
    ushort* __restrict__ Wb, ushort* __restrict__ Xb,
    unsigned* __restrict__ bar) {
  __shared__ ushort SM[16384];            // 32 KB, re-used by every phase
  const int bid = blockIdx.x, tid = threadIdx.x;
  const int wv = tid >> 6, l = tid & 63;

  // ================= phase 0: prep =================
  {
    // cvt_w: 4 x 65536 float4-chunks, exactly 1 per thread
    int i = bid * 256 + tid;
    {
      int wsel = i >> 16, j = i & 65535;
      const float* src = (wsel == 0) ? Wq : (wsel == 1) ? Wk
                       : (wsel == 2) ? Wv : Wo;
      float4 vv = ((const float4*)src)[j];
      uint2 o = { cvtpk(vv.x, vv.y), cvtpk(vv.z, vv.w) };
      ((uint2*)(Wb + (size_t)wsel * 262144))[j] = o;
    }
    // cvt_x: 3 x 1048576 chunks, 12 per thread
#pragma unroll
    for (int t = 0; t < 12; ++t) {
      int g = i + t * 262144;
      int zsel = g >> 20, j = g & 1048575;
      const float* src = (zsel == 0) ? q : (zsel == 1) ? k : v;
      float4 vv = ((const float4*)src)[j];
      uint2 o = { cvtpk(vv.x, vv.y), cvtpk(vv.z, vv.w) };
      ((uint2*)(Xb + (size_t)zsel * 4194304))[j] = o;
    }
    // mask_bits: 4096 wave-jobs, 1 per wave
    const int lane = l;
    const int wvg = i >> 6;
    const size_t base = (size_t)wvg * 64;
    for (int j = 0; j < 64; j += 4) {
      int v0 = mask[(base + j + 0) * 64 + lane];
      int v1 = mask[(base + j + 1) * 64 + lane];
      int v2 = mask[(base + j + 2) * 64 + lane];
      int v3 = mask[(base + j + 3) * 64 + lane];
      unsigned long long b0 = __ballot(v0 != 0), b1 = __ballot(v1 != 0);
      unsigned long long b2 = __ballot(v2 != 0), b3 = __ballot(v3 != 0);
      if (lane == 0) {
        MB[base + j] = b0; MB[base + j + 1] = b1;
        MB[base + j + 2] = b2; MB[base + j + 3] = b3;
      }
    }
  }
  gbar(bar, tid);

  // ================= phase 1: qkv GEMM (768 jobs) =================
  // Y[8192][512] = Xb bf16 [m][k] * W bf16 [n][k]; tile 128x128, BK=64.
  if (bid < 768) {
    ushort* As = SM;                    // [128][64] bf16, chunk-swizzled
    ushort* Wt = SM + 8192;             // [128][64] bf16, chunk-swizzled
    const int z = bid >> 8, rr = bid & 255;
    const int bx = rr & 63, by = rr >> 6;
    const ushort* X = Xb + (size_t)z * 4194304;
    const ushort* W = Wb + (size_t)z * 262144;
    const float* bias = (z == 0) ? bq : (z == 1) ? bk : bv;
    const float scale = (z == 0) ? 0.18033688011112042f : 1.0f;
    ushort* Y = (z == 0) ? Qh : (z == 1) ? Kh : Vt;

    const int quad = l >> 4, ln = l & 15;
    const int m0 = bx * 128, n0 = by * 128;
    const int wm = (wv & 1) * 64, wn = (wv >> 1) * 64;
    const int sr = l >> 3, sc = l & 7;
    f32x4 acc[4][4] = {};

    for (int kk = 0; kk < 512; kk += 64) {
#pragma unroll
      for (int i = 0; i < 4; ++i) {
        int row = wv * 32 + i * 8 + sr;
        gll16(X + (size_t)(m0 + row) * 512 + kk + ((sc ^ (row & 7)) * 8),
              As + (wv * 32 + i * 8) * 64);
        gll16(W + (size_t)(n0 + row) * 512 + kk + ((sc ^ (row & 7)) * 8),
              Wt + (wv * 32 + i * 8) * 64);
      }
      __syncthreads();
#pragma unroll
      for (int ks = 0; ks < 2; ++ks) {
        bf16x8 a[4], bw[4];
#pragma unroll
        for (int mt = 0; mt < 4; ++mt) {
          int row = wm + mt * 16 + ln;
          a[mt] = *(const bf16x8*)&As[row * 64 + (((ks * 4 + quad) ^ (row & 7)) * 8)];
        }
#pragma unroll
        for (int nt = 0; nt < 4; ++nt) {
          int row = wn + nt * 16 + ln;
          bw[nt] = *(const bf16x8*)&Wt[row * 64 + (((ks * 4 + quad) ^ (row & 7)) * 8)];
        }
#pragma unroll
        for (int mt = 0; mt < 4; ++mt)
#pragma unroll
          for (int nt = 0; nt < 4; ++nt)
            acc[mt][nt] = MFMA16(a[mt], bw[nt], acc[mt][nt]);
      }
      __syncthreads();
    }
    float bval[4];
#pragma unroll
    for (int nt = 0; nt < 4; ++nt) bval[nt] = bias[n0 + wn + nt * 16 + ln];

    if (z == 2) {
      // transpose via LDS: T[128 n][128 m] ushort (=32KB), xor-swizzled chunks
      ushort* uT = SM;
#pragma unroll
      for (int nt = 0; nt < 4; ++nt) {
        int row = wn + nt * 16 + ln;
#pragma unroll
        for (int mt = 0; mt < 4; ++mt) {
          int mbase = wm + mt * 16 + quad * 4;
          uint2 pk = { cvtpk(acc[mt][nt][0] + bval[nt], acc[mt][nt][1] + bval[nt]),
                       cvtpk(acc[mt][nt][2] + bval[nt], acc[mt][nt][3] + bval[nt]) };
          int c = (mbase >> 3) ^ (row & 7);
          *(uint2*)&uT[row * 128 + c * 8 + (quad & 1) * 4] = pk;
        }
      }
      __syncthreads();
#pragma unroll
      for (int j = 0; j < 8; ++j) {
        int i = tid + j * 256;
        int row = i >> 4, cs = i & 15;
        int g = cs ^ (row & 7);
        uint4 d = *(const uint4*)&uT[row * 128 + cs * 8];
        int n = n0 + row, m = m0 + g * 8;
        int bb = m >> 11, s = m & 2047, h = n >> 6, hd = n & 63;
        *(uint4*)(Y + ((size_t)((bb * 8 + h) * 64 + hd)) * 2048 + s) = d;
      }
    } else {
      // EPI0 two-pass: [m 128][n 68] LDS round-trip per 64-col half
      ushort* uM = SM;
#pragma unroll
      for (int half = 0; half < 2; ++half) {
        __syncthreads();
        if ((wv >> 1) == half) {
#pragma unroll
          for (int mt = 0; mt < 4; ++mt)
#pragma unroll
            for (int nt = 0; nt < 4; ++nt) {
              int n = nt * 16 + ln;
#pragma unroll
              for (int r = 0; r < 4; ++r) {
                int m = wm + mt * 16 + quad * 4 + r;
                uM[m * 68 + n] = f2bf((acc[mt][nt][r] + bval[nt]) * scale);
              }
            }
        }
        __syncthreads();
#pragma unroll
        for (int j = 0; j < 4; ++j) {
          int i = tid + j * 256;
          int row = i >> 3, cs = i & 7;
          uint4 d = *(const uint4*)&uM[row * 68 + cs * 8];
          int m = m0 + row, n = n0 + half * 64 + cs * 8;
          int bb = m >> 11, s = m & 2047, h = n >> 6, hd = n & 63;
          *(uint4*)(Y + (((size_t)(bb * 8 + h) * 2048) + s) * 64 + hd) = d;
        }
      }
    }
  }
  gbar(bar, tid);

  // ================= phase 2: attention (1024 jobs, 1 per block) =================
  {
    ushort* Ks = SM;                      // [kv 128][d 64], chunk-swizzled
    ushort* Vs = SM + 8192;               // [hd 64][kv 128], chunk-swizzled
    const int lane = l;
    const int hs = lane >> 5, lq = lane & 31;
    const int qh = wv >> 1, kvh = wv & 1;
    const int bh = bid & 31, qb = bid >> 5;
    const size_t hoff = (size_t)bh * 2048 * 64;
    const int q0 = qb * 64;
    const int qg = q0 + qh * 32 + lq;
    const int srK = lane >> 3, scK = lane & 7;
    const int srV = lane >> 4, scV = lane & 15;

    bf16x8 qf[4];                          // B-frag: k = 16*ki + 8*hs + j
#pragma unroll
    for (int ki = 0; ki < 4; ++ki)
      qf[ki] = *(const bf16x8*)(Qh + hoff + (size_t)qg * 64 + ki * 16 + hs * 8);

    bf16x8 ones;
#pragma unroll
    for (int j = 0; j < 8; ++j) ones[j] = (__bf16)1.0f;

    f32x16 po0 = {}, po1 = {};             // O^T accum, col=q
    f32x16 lacc = {};                      // row-sum accum (all regs equal)
    const unsigned long long* mrow = MB + ((size_t)(bh >> 3) * 2048 + qg) * 32;

    for (int it = 0; it < 16; ++it) {
      const int kv0 = it * 128;
#pragma unroll
      for (int i = 0; i < 4; ++i) {
        int row = wv * 32 + i * 8 + srK;
        gll16(Kh + hoff + (size_t)(kv0 + row) * 64 + ((scK ^ (row & 7)) * 8),
              Ks + (wv * 32 + i * 8) * 64);
        int rv = wv * 16 + i * 4 + srV;
        gll16(Vt + hoff + (size_t)rv * 2048 + kv0 + ((scV ^ (rv & 7)) * 8),
              Vs + (wv * 16 + i * 4) * 128);
      }
      unsigned long long mbw = mrow[it * 2 + kvh];
      __syncthreads();

#pragma unroll
      for (int ch = 0; ch < 2; ++ch) {
        const int kvb = kvh * 64 + ch * 32;
        f32x16 sc_ = {};
#pragma unroll
        for (int ki = 0; ki < 4; ++ki) {
          int row = kvb + lq;
          bf16x8 ak = *(const bf16x8*)&Ks[row * 64 + (((2 * ki + hs) ^ (row & 7)) * 8)];
          sc_ = MFMA32(ak, qf[ki], sc_);
        }
        uint pk[8];
#pragma unroll
        for (int c = 0; c < 4; ++c) {
          unsigned nib = (unsigned)(mbw >> (ch * 32 + c * 8 + hs * 4)) & 0xFu;
          float p0 = (nib & 1u) ? exp2r(sc_[4 * c + 0]) : 0.f;
          float p1 = (nib & 2u) ? exp2r(sc_[4 * c + 1]) : 0.f;
          float p2 = (nib & 4u) ? exp2r(sc_[4 * c + 2]) : 0.f;
          float p3 = (nib & 8u) ? exp2r(sc_[4 * c + 3]) : 0.f;
          pk[2 * c + 0] = cvtpk(p0, p1);
          pk[2 * c + 1] = cvtpk(p2, p3);
        }
#pragma unroll
        for (int t2 = 0; t2 < 2; ++t2) {
          union { uint u[4]; bf16x8 v; } bp;
#if __has_builtin(__builtin_amdgcn_permlane32_swap)
          uint32x2 r02 = __builtin_amdgcn_permlane32_swap(pk[4 * t2 + 0], pk[4 * t2 + 2], false, false);
          uint32x2 r13 = __builtin_amdgcn_permlane32_swap(pk[4 * t2 + 1], pk[4 * t2 + 3], false, false);
          bp.u[0] = r02[0];
          bp.u[1] = r13[0];
          bp.u[2] = r02[1];
          bp.u[3] = r13[1];
#else
          uint bx0 = (uint)__shfl_xor((int)(hs ? pk[4 * t2 + 0] : pk[4 * t2 + 2]), 32);
          uint bx1 = (uint)__shfl_xor((int)(hs ? pk[4 * t2 + 1] : pk[4 * t2 + 3]), 32);
          bp.u[0] = hs ? bx0 : pk[4 * t2 + 0];
          bp.u[1] = hs ? bx1 : pk[4 * t2 + 1];
          bp.u[2] = hs ? pk[4 * t2 + 2] : bx0;
          bp.u[3] = hs ? pk[4 * t2 + 3] : bx1;
#endif
          lacc = MFMA32(ones, bp.v, lacc); // row-sum of P, col=q
#pragma unroll
          for (int m2 = 0; m2 < 2; ++m2) {
            int hd = m2 * 32 + lq;
            int gch = (kvb >> 3) + 2 * t2 + hs;
            bf16x8 av = *(const bf16x8*)&Vs[hd * 128 + ((gch ^ (hd & 7)) * 8)];
            if (m2 == 0) po0 = MFMA32(av, bp.v, po0);
            else         po1 = MFMA32(av, bp.v, po1);
          }
        }
      }
      __syncthreads();
    }

    float l_own = lacc[0];                 // full sum over this wave's kv half
    float* psh = (float*)Ks;               // [64 q][64 hd] f32
    float* lsh = (float*)Vs;               // [qh][64]
    ushort* Osh = Vs + 256;                // [64 q][72]
    if (kvh == 1) {
#pragma unroll
      for (int i = 0; i < 16; ++i) psh[(qh * 32 + i) * 64 + lane] = po0[i];
#pragma unroll
      for (int i = 0; i < 16; ++i) psh[(qh * 32 + 16 + i) * 64 + lane] = po1[i];
      lsh[qh * 64 + lane] = l_own;
    }
    __syncthreads();
    if (kvh == 0) {
      float linv = 1.0f / (l_own + lsh[qh * 64 + lane]);
      int row = qh * 32 + lq;
#pragma unroll
      for (int m2 = 0; m2 < 2; ++m2) {
#pragma unroll
        for (int c = 0; c < 4; ++c)
#pragma unroll
          for (int b2 = 0; b2 < 2; ++b2) {
            int r = 4 * c + 2 * b2;
            float v0, v1;
            if (m2 == 0) {
              v0 = (po0[r] + psh[(qh * 32 + r) * 64 + lane]) * linv;
              v1 = (po0[r + 1] + psh[(qh * 32 + r + 1) * 64 + lane]) * linv;
            } else {
              v0 = (po1[r] + psh[(qh * 32 + 16 + r) * 64 + lane]) * linv;
              v1 = (po1[r + 1] + psh[(qh * 32 + 16 + r + 1) * 64 + lane]) * linv;
            }
            int hd = m2 * 32 + 8 * c + 4 * hs + 2 * b2;
            *(uint*)&Osh[row * 72 + hd] = cvtpk(v0, v1);
          }
      }
    }
    __syncthreads();
    for (int i = tid; i < 512; i += 256) {
      int row = i >> 3, cc = i & 7;
      uint4 d = *(const uint4*)&Osh[row * 72 + cc * 8];
      *(uint4*)(Oh + ((size_t)((bh >> 3) * 2048 + q0 + row)) * 512 +
                (bh & 7) * 64 + cc * 8) = d;
    }
  }
  gbar(bar, tid);

  // ================= phase 3: out projection (512 jobs) =================
  if (bid < 512) {
    ushort* As = SM;                      // [64][64]
    ushort* Ws = SM + 4096;               // [128][64]
    const ushort* W = Wb + 3 * 262144;
    const int bx = bid & 127, by = bid >> 7;
    const int quad = l >> 4, ln = l & 15;
    const int m0 = bx * 64, n0 = by * 128;
    const int wm = (wv & 1) * 32, wn = (wv >> 1) * 64;
    const int sr = l >> 3, sc = l & 7;
    f32x4 acc[2][4] = {};
    for (int kk = 0; kk < 512; kk += 64) {
#pragma unroll
      for (int i = 0; i < 2; ++i) {
        int row = wv * 16 + i * 8 + sr;
        gll16(Oh + (size_t)(m0 + row) * 512 + kk + ((sc ^ (row & 7)) * 8),
              As + (wv * 16 + i * 8) * 64);
      }
#pragma unroll
      for (int i = 0; i < 4; ++i) {
        int row = wv * 32 + i * 8 + sr;
        gll16(W + (size_t)(n0 + row) * 512 + kk + ((sc ^ (row & 7)) * 8),
              Ws + (wv * 32 + i * 8) * 64);
      }
      __syncthreads();
#pragma unroll
      for (int ks = 0; ks < 2; ++ks) {
        bf16x8 a[2], bw[4];
#pragma unroll
        for (int mt = 0; mt < 2; ++mt) {
          int row = wm + mt * 16 + ln;
          a[mt] = *(const bf16x8*)&As[row * 64 + (((ks * 4 + quad) ^ (row & 7)) * 8)];
        }
#pragma unroll
        for (int nt = 0; nt < 4; ++nt) {
          int row = wn + nt * 16 + ln;
          bw[nt] = *(const bf16x8*)&Ws[row * 64 + (((ks * 4 + quad) ^ (row & 7)) * 8)];
        }
#pragma unroll
        for (int mt = 0; mt < 2; ++mt)
#pragma unroll
          for (int nt = 0; nt < 4; ++nt)
            acc[mt][nt] = MFMA16(a[mt], bw[nt], acc[mt][nt]);
      }
      __syncthreads();
    }
#pragma unroll
    for (int mt = 0; mt < 2; ++mt)
#pragma unroll
      for (int nt = 0; nt < 4; ++nt) {
        int n = n0 + wn + nt * 16 + ln;
        float bval = bo[n];
#pragma unroll
        for (int r = 0; r < 4; ++r) {
          int m = m0 + wm + mt * 16 + quad * 4 + r;
          out[(size_t)m * 512 + n] = acc[mt][nt][r] + bval;
        }
      }
  }
}

// ---------------------------------------------------------------- launch
extern "C" void kernel_launch(void* const* d_in, const int* in_sizes, int n_in,
                              void* d_out, int out_size, void* d_ws, size_t ws_size,
                              hipStream_t stream) {
  const float* q    = (const float*)d_in[0];
  const float* k    = (const float*)d_in[1];
  const float* v    = (const float*)d_in[2];
  const int*   mask = (const int*)d_in[3];
  const float* Wq   = (const float*)d_in[4];
  const float* bq   = (const float*)d_in[5];
  const float* Wk   = (const float*)d_in[6];
  const float* bk   = (const float*)d_in[7];
  const float* Wv   = (const float*)d_in[8];
  const float* bv   = (const float*)d_in[9];
  const float* Wo   = (const float*)d_in[10];
  const float* bo   = (const float*)d_in[11];
  float* out = (float*)d_out;

  uint8_t* ws = (uint8_t*)d_ws;
  const size_t MiB = 1u << 20;
  ushort* Oh = (ushort*)(ws + 0 * MiB);
  ushort* Qh = (ushort*)(ws + 8 * MiB);
  ushort* Kh = (ushort*)(ws + 16 * MiB);
  ushort* Vt = (ushort*)(ws + 24 * MiB);
  unsigned long long* MB = (unsigned long long*)(ws + 32 * MiB);
  ushort* Wb = (ushort*)(ws + 34 * MiB);
  ushort* Xb = (ushort*)(ws + 36 * MiB);
  unsigned* bar = (unsigned*)(ws + 60 * MiB);

  hipMemsetAsync(bar, 0, 16, stream);
  mega<<<dim3(1024), dim3(256), 0, stream>>>(
      q, k, v, mask, Wq, bq, Wk, bk, Wv, bv, Wo, bo,
      out, Oh, Qh, Kh, Vt, MB, Wb, Xb, bar);
}

// Round 7
// 635.296 us; speedup vs baseline: 1.1954x; 1.1954x over previous
//
#include <hip/hip_runtime.h>
#include <cstdint>

// B=4, S=2048, H=512, NH=8, HD=64 — ONE plain launch, 4 phases, hand grid-barrier:
//   prep (cvt_w + cvt_x + mask_bits) | qkv (bf16 128x128, 768 jobs) |
//   attn (1024 jobs, r2 structure) | out_gemm (512 jobs)
// grid 1024x256, 32KB LDS, __launch_bounds__(256,4) => exactly 4 blk/CU x 256 CU
// co-residency; barrier = monotonic ticket counter zeroed via hipMemsetAsync.
// FENCES ONCE PER BLOCK (tid==0): wbl2/inv are cache-wide; 256x/block was a
// flush storm (r6: 759us, MfmaUtil 3.6%).
// ws: Oh 0-8Mi | Qh 8-16 | Kh 16-24 | Vt 24-32 | MB 32-34 | Wb 34-36 | Xb 36-60 |
//     bar @ 60 MiB

typedef __bf16 bf16x8 __attribute__((ext_vector_type(8)));
typedef float  f32x4  __attribute__((ext_vector_type(4)));
typedef float  f32x16 __attribute__((ext_vector_type(16)));
typedef unsigned int uint32x2 __attribute__((ext_vector_type(2)));

#define MFMA16(a, b, c) __builtin_amdgcn_mfma_f32_16x16x32_bf16(a, b, c, 0, 0, 0)
#define MFMA32(a, b, c) __builtin_amdgcn_mfma_f32_32x32x16_bf16(a, b, c, 0, 0, 0)

__device__ __forceinline__ ushort f2bf(float f) {
  union { float f; uint32_t u; } v; v.f = f;
  return (ushort)((v.u + 0x8000u) >> 16);
}
__device__ __forceinline__ uint cvtpk(float a, float b) {
  uint r;
  asm("v_cvt_pk_bf16_f32 %0, %1, %2" : "=v"(r) : "v"(a), "v"(b));
  return r;
}
__device__ __forceinline__ float exp2r(float x) {
#if __has_builtin(__builtin_amdgcn_exp2f)
  return __builtin_amdgcn_exp2f(x);
#else
  return exp2f(x);
#endif
}

typedef const __attribute__((address_space(1))) unsigned int* gas_u32;
typedef __attribute__((address_space(3))) unsigned int* las_u32;
__device__ __forceinline__ void gll16(const void* g, void* l) {
  __builtin_amdgcn_global_load_lds((gas_u32)g, (las_u32)l, 16, 0, 0);
}

// grid barrier: monotonic ticket counter; each instance owns a 1024-ticket range.
// All fences execute in ONE thread per block: after __syncthreads() every wave's
// stores have drained (vmcnt 0) into this XCD's L2, so one cache-wide wbl2
// releases the whole block; one inv before the closing __syncthreads() acquires
// for the whole block (same CU L1 / same XCD L2).
__device__ __forceinline__ void gbar(unsigned* bar, int tid) {
  __syncthreads();                     // block's phase work complete, vmcnt drained
  if (tid == 0) {
    __threadfence();                   // release: wb this XCD's L2 (once/block)
    unsigned old = __hip_atomic_fetch_add(bar, 1u, __ATOMIC_RELAXED,
                                          __HIP_MEMORY_SCOPE_AGENT);
    unsigned target = (old / 1024u + 1u) * 1024u;
    while (__hip_atomic_load(bar, __ATOMIC_RELAXED, __HIP_MEMORY_SCOPE_AGENT) < target)
      __builtin_amdgcn_s_sleep(8);
    __threadfence();                   // acquire: inv L1(CU)+L2(XCD) (once/block)
  }
  __syncthreads();
}

// ---------------------------------------------------------------- megakernel
__global__ __launch_bounds__(256, 4) void mega(
    const float* __restrict__ q, const float* __restrict__ k,
    const float* __restrict__ v, const int* __restrict__ mask,
    const float* __restrict__ Wq, const float* __restrict__ bq,
    const float* __restrict__ Wk, const float* __restrict__ bk,
    const float* __restrict__ Wv, const float* __restrict__ bv,
    const float* __restrict__ Wo, const float* __restrict__ bo,
    float* __restrict__ out, ushort* __restrict__ Oh,
    ushort* __restrict__ Qh, ushort* __restrict__ Kh,
    ushort* __restrict__ Vt, unsigned long long* __restrict__ MB,
    ushort* __restrict__ Wb, ushort* __restrict__ Xb,
    unsigned* __restrict__ bar) {
  __shared__ ushort SM[16384];            // 32 KB, re-used by every phase
  const int bid = blockIdx.x, tid = threadIdx.x;
  const int wv = tid >> 6, l = tid & 63;

  // ================= phase 0: prep =================
  {
    // cvt_w: 4 x 65536 float4-chunks, exactly 1 per thread
    int i = bid * 256 + tid;
    {
      int wsel = i >> 16, j = i & 65535;
      const float* src = (wsel == 0) ? Wq : (wsel == 1) ? Wk
                       : (wsel == 2) ? Wv : Wo;
      float4 vv = ((const float4*)src)[j];
      uint2 o = { cvtpk(vv.x, vv.y), cvtpk(vv.z, vv.w) };
      ((uint2*)(Wb + (size_t)wsel * 262144))[j] = o;
    }
    // cvt_x: 3 x 1048576 chunks, 12 per thread
#pragma unroll
    for (int t = 0; t < 12; ++t) {
      int g = i + t * 262144;
      int zsel = g >> 20, j = g & 1048575;
      const float* src = (zsel == 0) ? q : (zsel == 1) ? k : v;
      float4 vv = ((const float4*)src)[j];
      uint2 o = { cvtpk(vv.x, vv.y), cvtpk(vv.z, vv.w) };
      ((uint2*)(Xb + (size_t)zsel * 4194304))[j] = o;
    }
    // mask_bits: 4096 wave-jobs, 1 per wave
    const int lane = l;
    const int wvg = i >> 6;
    const size_t base = (size_t)wvg * 64;
    for (int j = 0; j < 64; j += 4) {
      int v0 = mask[(base + j + 0) * 64 + lane];
      int v1 = mask[(base + j + 1) * 64 + lane];
      int v2 = mask[(base + j + 2) * 64 + lane];
      int v3 = mask[(base + j + 3) * 64 + lane];
      unsigned long long b0 = __ballot(v0 != 0), b1 = __ballot(v1 != 0);
      unsigned long long b2 = __ballot(v2 != 0), b3 = __ballot(v3 != 0);
      if (lane == 0) {
        MB[base + j] = b0; MB[base + j + 1] = b1;
        MB[base + j + 2] = b2; MB[base + j + 3] = b3;
      }
    }
  }
  gbar(bar, tid);

  // ================= phase 1: qkv GEMM (768 jobs) =================
  // Y[8192][512] = Xb bf16 [m][k] * W bf16 [n][k]; tile 128x128, BK=64.
  if (bid < 768) {
    ushort* As = SM;                    // [128][64] bf16, chunk-swizzled
    ushort* Wt = SM + 8192;             // [128][64] bf16, chunk-swizzled
    const int z = bid >> 8, rr = bid & 255;
    const int bx = rr & 63, by = rr >> 6;
    const ushort* X = Xb + (size_t)z * 4194304;
    const ushort* W = Wb + (size_t)z * 262144;
    const float* bias = (z == 0) ? bq : (z == 1) ? bk : bv;
    const float scale = (z == 0) ? 0.18033688011112042f : 1.0f;
    ushort* Y = (z == 0) ? Qh : (z == 1) ? Kh : Vt;

    const int quad = l >> 4, ln = l & 15;
    const int m0 = bx * 128, n0 = by * 128;
    const int wm = (wv & 1) * 64, wn = (wv >> 1) * 64;
    const int sr = l >> 3, sc = l & 7;
    f32x4 acc[4][4] = {};

    for (int kk = 0; kk < 512; kk += 64) {
#pragma unroll
      for (int i = 0; i < 4; ++i) {
        int row = wv * 32 + i * 8 + sr;
        gll16(X + (size_t)(m0 + row) * 512 + kk + ((sc ^ (row & 7)) * 8),
              As + (wv * 32 + i * 8) * 64);
        gll16(W + (size_t)(n0 + row) * 512 + kk + ((sc ^ (row & 7)) * 8),
              Wt + (wv * 32 + i * 8) * 64);
      }
      __syncthreads();
#pragma unroll
      for (int ks = 0; ks < 2; ++ks) {
        bf16x8 a[4], bw[4];
#pragma unroll
        for (int mt = 0; mt < 4; ++mt) {
          int row = wm + mt * 16 + ln;
          a[mt] = *(const bf16x8*)&As[row * 64 + (((ks * 4 + quad) ^ (row & 7)) * 8)];
        }
#pragma unroll
        for (int nt = 0; nt < 4; ++nt) {
          int row = wn + nt * 16 + ln;
          bw[nt] = *(const bf16x8*)&Wt[row * 64 + (((ks * 4 + quad) ^ (row & 7)) * 8)];
        }
#pragma unroll
        for (int mt = 0; mt < 4; ++mt)
#pragma unroll
          for (int nt = 0; nt < 4; ++nt)
            acc[mt][nt] = MFMA16(a[mt], bw[nt], acc[mt][nt]);
      }
      __syncthreads();
    }
    float bval[4];
#pragma unroll
    for (int nt = 0; nt < 4; ++nt) bval[nt] = bias[n0 + wn + nt * 16 + ln];

    if (z == 2) {
      // transpose via LDS: T[128 n][128 m] ushort (=32KB), xor-swizzled chunks
      ushort* uT = SM;
#pragma unroll
      for (int nt = 0; nt < 4; ++nt) {
        int row = wn + nt * 16 + ln;
#pragma unroll
        for (int mt = 0; mt < 4; ++mt) {
          int mbase = wm + mt * 16 + quad * 4;
          uint2 pk = { cvtpk(acc[mt][nt][0] + bval[nt], acc[mt][nt][1] + bval[nt]),
                       cvtpk(acc[mt][nt][2] + bval[nt], acc[mt][nt][3] + bval[nt]) };
          int c = (mbase >> 3) ^ (row & 7);
          *(uint2*)&uT[row * 128 + c * 8 + (quad & 1) * 4] = pk;
        }
      }
      __syncthreads();
#pragma unroll
      for (int j = 0; j < 8; ++j) {
        int i = tid + j * 256;
        int row = i >> 4, cs = i & 15;
        int g = cs ^ (row & 7);
        uint4 d = *(const uint4*)&uT[row * 128 + cs * 8];
        int n = n0 + row, m = m0 + g * 8;
        int bb = m >> 11, s = m & 2047, h = n >> 6, hd = n & 63;
        *(uint4*)(Y + ((size_t)((bb * 8 + h) * 64 + hd)) * 2048 + s) = d;
      }
    } else {
      // EPI0 two-pass: [m 128][n 68] LDS round-trip per 64-col half
      ushort* uM = SM;
#pragma unroll
      for (int half = 0; half < 2; ++half) {
        __syncthreads();
        if ((wv >> 1) == half) {
#pragma unroll
          for (int mt = 0; mt < 4; ++mt)
#pragma unroll
            for (int nt = 0; nt < 4; ++nt) {
              int n = nt * 16 + ln;
#pragma unroll
              for (int r = 0; r < 4; ++r) {
                int m = wm + mt * 16 + quad * 4 + r;
                uM[m * 68 + n] = f2bf((acc[mt][nt][r] + bval[nt]) * scale);
              }
            }
        }
        __syncthreads();
#pragma unroll
        for (int j = 0; j < 4; ++j) {
          int i = tid + j * 256;
          int row = i >> 3, cs = i & 7;
          uint4 d = *(const uint4*)&uM[row * 68 + cs * 8];
          int m = m0 + row, n = n0 + half * 64 + cs * 8;
          int bb = m >> 11, s = m & 2047, h = n >> 6, hd = n & 63;
          *(uint4*)(Y + (((size_t)(bb * 8 + h) * 2048) + s) * 64 + hd) = d;
        }
      }
    }
  }
  gbar(bar, tid);

  // ================= phase 2: attention (1024 jobs, 1 per block) =================
  {
    ushort* Ks = SM;                      // [kv 128][d 64], chunk-swizzled
    ushort* Vs = SM + 8192;               // [hd 64][kv 128], chunk-swizzled
    const int lane = l;
    const int hs = lane >> 5, lq = lane & 31;
    const int qh = wv >> 1, kvh = wv & 1;
    const int bh = bid & 31, qb = bid >> 5;
    const size_t hoff = (size_t)bh * 2048 * 64;
    const int q0 = qb * 64;
    const int qg = q0 + qh * 32 + lq;
    const int srK = lane >> 3, scK = lane & 7;
    const int srV = lane >> 4, scV = lane & 15;

    bf16x8 qf[4];                          // B-frag: k = 16*ki + 8*hs + j
#pragma unroll
    for (int ki = 0; ki < 4; ++ki)
      qf[ki] = *(const bf16x8*)(Qh + hoff + (size_t)qg * 64 + ki * 16 + hs * 8);

    bf16x8 ones;
#pragma unroll
    for (int j = 0; j < 8; ++j) ones[j] = (__bf16)1.0f;

    f32x16 po0 = {}, po1 = {};             // O^T accum, col=q
    f32x16 lacc = {};                      // row-sum accum (all regs equal)
    const unsigned long long* mrow = MB + ((size_t)(bh >> 3) * 2048 + qg) * 32;

    for (int it = 0; it < 16; ++it) {
      const int kv0 = it * 128;
#pragma unroll
      for (int i = 0; i < 4; ++i) {
        int row = wv * 32 + i * 8 + srK;
        gll16(Kh + hoff + (size_t)(kv0 + row) * 64 + ((scK ^ (row & 7)) * 8),
              Ks + (wv * 32 + i * 8) * 64);
        int rv = wv * 16 + i * 4 + srV;
        gll16(Vt + hoff + (size_t)rv * 2048 + kv0 + ((scV ^ (rv & 7)) * 8),
              Vs + (wv * 16 + i * 4) * 128);
      }
      unsigned long long mbw = mrow[it * 2 + kvh];
      __syncthreads();

#pragma unroll
      for (int ch = 0; ch < 2; ++ch) {
        const int kvb = kvh * 64 + ch * 32;
        f32x16 sc_ = {};
#pragma unroll
        for (int ki = 0; ki < 4; ++ki) {
          int row = kvb + lq;
          bf16x8 ak = *(const bf16x8*)&Ks[row * 64 + (((2 * ki + hs) ^ (row & 7)) * 8)];
          sc_ = MFMA32(ak, qf[ki], sc_);
        }
        uint pk[8];
#pragma unroll
        for (int c = 0; c < 4; ++c) {
          unsigned nib = (unsigned)(mbw >> (ch * 32 + c * 8 + hs * 4)) & 0xFu;
          float p0 = (nib & 1u) ? exp2r(sc_[4 * c + 0]) : 0.f;
          float p1 = (nib & 2u) ? exp2r(sc_[4 * c + 1]) : 0.f;
          float p2 = (nib & 4u) ? exp2r(sc_[4 * c + 2]) : 0.f;
          float p3 = (nib & 8u) ? exp2r(sc_[4 * c + 3]) : 0.f;
          pk[2 * c + 0] = cvtpk(p0, p1);
          pk[2 * c + 1] = cvtpk(p2, p3);
        }
#pragma unroll
        for (int t2 = 0; t2 < 2; ++t2) {
          union { uint u[4]; bf16x8 v; } bp;
#if __has_builtin(__builtin_amdgcn_permlane32_swap)
          uint32x2 r02 = __builtin_amdgcn_permlane32_swap(pk[4 * t2 + 0], pk[4 * t2 + 2], false, false);
          uint32x2 r13 = __builtin_amdgcn_permlane32_swap(pk[4 * t2 + 1], pk[4 * t2 + 3], false, false);
          bp.u[0] = r02[0];
          bp.u[1] = r13[0];
          bp.u[2] = r02[1];
          bp.u[3] = r13[1];
#else
          uint bx0 = (uint)__shfl_xor((int)(hs ? pk[4 * t2 + 0] : pk[4 * t2 + 2]), 32);
          uint bx1 = (uint)__shfl_xor((int)(hs ? pk[4 * t2 + 1] : pk[4 * t2 + 3]), 32);
          bp.u[0] = hs ? bx0 : pk[4 * t2 + 0];
          bp.u[1] = hs ? bx1 : pk[4 * t2 + 1];
          bp.u[2] = hs ? pk[4 * t2 + 2] : bx0;
          bp.u[3] = hs ? pk[4 * t2 + 3] : bx1;
#endif
          lacc = MFMA32(ones, bp.v, lacc); // row-sum of P, col=q
#pragma unroll
          for (int m2 = 0; m2 < 2; ++m2) {
            int hd = m2 * 32 + lq;
            int gch = (kvb >> 3) + 2 * t2 + hs;
            bf16x8 av = *(const bf16x8*)&Vs[hd * 128 + ((gch ^ (hd & 7)) * 8)];
            if (m2 == 0) po0 = MFMA32(av, bp.v, po0);
            else         po1 = MFMA32(av, bp.v, po1);
          }
        }
      }
      __syncthreads();
    }

    float l_own = lacc[0];                 // full sum over this wave's kv half
    float* psh = (float*)Ks;               // [64 q][64 hd] f32
    float* lsh = (float*)Vs;               // [qh][64]
    ushort* Osh = Vs + 256;                // [64 q][72]
    if (kvh == 1) {
#pragma unroll
      for (int i = 0; i < 16; ++i) psh[(qh * 32 + i) * 64 + lane] = po0[i];
#pragma unroll
      for (int i = 0; i < 16; ++i) psh[(qh * 32 + 16 + i) * 64 + lane] = po1[i];
      lsh[qh * 64 + lane] = l_own;
    }
    __syncthreads();
    if (kvh == 0) {
      float linv = 1.0f / (l_own + lsh[qh * 64 + lane]);
      int row = qh * 32 + lq;
#pragma unroll
      for (int m2 = 0; m2 < 2; ++m2) {
#pragma unroll
        for (int c = 0; c < 4; ++c)
#pragma unroll
          for (int b2 = 0; b2 < 2; ++b2) {
            int r = 4 * c + 2 * b2;
            float v0, v1;
            if (m2 == 0) {
              v0 = (po0[r] + psh[(qh * 32 + r) * 64 + lane]) * linv;
              v1 = (po0[r + 1] + psh[(qh * 32 + r + 1) * 64 + lane]) * linv;
            } else {
              v0 = (po1[r] + psh[(qh * 32 + 16 + r) * 64 + lane]) * linv;
              v1 = (po1[r + 1] + psh[(qh * 32 + 16 + r + 1) * 64 + lane]) * linv;
            }
            int hd = m2 * 32 + 8 * c + 4 * hs + 2 * b2;
            *(uint*)&Osh[row * 72 + hd] = cvtpk(v0, v1);
          }
      }
    }
    __syncthreads();
    for (int i = tid; i < 512; i += 256) {
      int row = i >> 3, cc = i & 7;
      uint4 d = *(const uint4*)&Osh[row * 72 + cc * 8];
      *(uint4*)(Oh + ((size_t)((bh >> 3) * 2048 + q0 + row)) * 512 +
                (bh & 7) * 64 + cc * 8) = d;
    }
  }
  gbar(bar, tid);

  // ================= phase 3: out projection (512 jobs) =================
  if (bid < 512) {
    ushort* As = SM;                      // [64][64]
    ushort* Ws = SM + 4096;               // [128][64]
    const ushort* W = Wb + 3 * 262144;
    const int bx = bid & 127, by = bid >> 7;
    const int quad = l >> 4, ln = l & 15;
    const int m0 = bx * 64, n0 = by * 128;
    const int wm = (wv & 1) * 32, wn = (wv >> 1) * 64;
    const int sr = l >> 3, sc = l & 7;
    f32x4 acc[2][4] = {};
    for (int kk = 0; kk < 512; kk += 64) {
#pragma unroll
      for (int i = 0; i < 2; ++i) {
        int row = wv * 16 + i * 8 + sr;
        gll16(Oh + (size_t)(m0 + row) * 512 + kk + ((sc ^ (row & 7)) * 8),
              As + (wv * 16 + i * 8) * 64);
      }
#pragma unroll
      for (int i = 0; i < 4; ++i) {
        int row = wv * 32 + i * 8 + sr;
        gll16(W + (size_t)(n0 + row) * 512 + kk + ((sc ^ (row & 7)) * 8),
              Ws + (wv * 32 + i * 8) * 64);
      }
      __syncthreads();
#pragma unroll
      for (int ks = 0; ks < 2; ++ks) {
        bf16x8 a[2], bw[4];
#pragma unroll
        for (int mt = 0; mt < 2; ++mt) {
          int row = wm + mt * 16 + ln;
          a[mt] = *(const bf16x8*)&As[row * 64 + (((ks * 4 + quad) ^ (row & 7)) * 8)];
        }
#pragma unroll
        for (int nt = 0; nt < 4; ++nt) {
          int row = wn + nt * 16 + ln;
          bw[nt] = *(const bf16x8*)&Ws[row * 64 + (((ks * 4 + quad) ^ (row & 7)) * 8)];
        }
#pragma unroll
        for (int mt = 0; mt < 2; ++mt)
#pragma unroll
          for (int nt = 0; nt < 4; ++nt)
            acc[mt][nt] = MFMA16(a[mt], bw[nt], acc[mt][nt]);
      }
      __syncthreads();
    }
#pragma unroll
    for (int mt = 0; mt < 2; ++mt)
#pragma unroll
      for (int nt = 0; nt < 4; ++nt) {
        int n = n0 + wn + nt * 16 + ln;
        float bval = bo[n];
#pragma unroll
        for (int r = 0; r < 4; ++r) {
          int m = m0 + wm + mt * 16 + quad * 4 + r;
          out[(size_t)m * 512 + n] = acc[mt][nt][r] + bval;
        }
      }
  }
}

// ---------------------------------------------------------------- launch
extern "C" void kernel_launch(void* const* d_in, const int* in_sizes, int n_in,
                              void* d_out, int out_size, void* d_ws, size_t ws_size,
                              hipStream_t stream) {
  const float* q    = (const float*)d_in[0];
  const float* k    = (const float*)d_in[1];
  const float* v    = (const float*)d_in[2];
  const int*   mask = (const int*)d_in[3];
  const float* Wq   = (const float*)d_in[4];
  const float* bq   = (const float*)d_in[5];
  const float* Wk   = (const float*)d_in[6];
  const float* bk   = (const float*)d_in[7];
  const float* Wv   = (const float*)d_in[8];
  const float* bv   = (const float*)d_in[9];
  const float* Wo   = (const float*)d_in[10];
  const float* bo   = (const float*)d_in[11];
  float* out = (float*)d_out;

  uint8_t* ws = (uint8_t*)d_ws;
  const size_t MiB = 1u << 20;
  ushort* Oh = (ushort*)(ws + 0 * MiB);
  ushort* Qh = (ushort*)(ws + 8 * MiB);
  ushort* Kh = (ushort*)(ws + 16 * MiB);
  ushort* Vt = (ushort*)(ws + 24 * MiB);
  unsigned long long* MB = (unsigned long long*)(ws + 32 * MiB);
  ushort* Wb = (ushort*)(ws + 34 * MiB);
  ushort* Xb = (ushort*)(ws + 36 * MiB);
  unsigned* bar = (unsigned*)(ws + 60 * MiB);

  hipMemsetAsync(bar, 0, 16, stream);
  mega<<<dim3(1024), dim3(256), 0, stream>>>(
      q, k, v, mask, Wq, bq, Wk, bk, Wv, bv, Wo, bo,
      out, Oh, Qh, Kh, Vt, MB, Wb, Xb, bar);
}

// Round 8
// 238.202 us; speedup vs baseline: 3.1882x; 2.6670x over previous
//
#include <hip/hip_runtime.h>
#include <cstdint>

// B=4, S=2048, H=512, NH=8, HD=64 — 4 launches:
//   prep (cvt_w + mask_bits) | qkv_gemm (128x128, fp32-staged, z=q/k/v) |
//   attn (512 thr, 128 q-rows/block, 2 blk/CU: K/V staged once per 128 rows) |
//   out_gemm
// ws: Oh 0-8Mi | Qh 8-16 | Kh 16-24 | Vt 24-32 | MB 32-34 | Wb 34-36 MiB

typedef __bf16 bf16x8 __attribute__((ext_vector_type(8)));
typedef float  f32x4  __attribute__((ext_vector_type(4)));
typedef float  f32x16 __attribute__((ext_vector_type(16)));
typedef unsigned int uint32x2 __attribute__((ext_vector_type(2)));

#define MFMA16(a, b, c) __builtin_amdgcn_mfma_f32_16x16x32_bf16(a, b, c, 0, 0, 0)
#define MFMA32(a, b, c) __builtin_amdgcn_mfma_f32_32x32x16_bf16(a, b, c, 0, 0, 0)

// round-half-up f32->bf16 (cheap: add + shift); ties differ from RTNE by <=1/2 ulp
__device__ __forceinline__ ushort f2bf(float f) {
  union { float f; uint32_t u; } v; v.f = f;
  return (ushort)((v.u + 0x8000u) >> 16);
}
// pack two f32 -> bf16x2 in ONE instruction (RTNE): low16 = cvt(a), high16 = cvt(b)
__device__ __forceinline__ uint cvtpk(float a, float b) {
  uint r;
  asm("v_cvt_pk_bf16_f32 %0, %1, %2" : "=v"(r) : "v"(a), "v"(b));
  return r;
}
__device__ __forceinline__ float exp2r(float x) {
#if __has_builtin(__builtin_amdgcn_exp2f)
  return __builtin_amdgcn_exp2f(x);
#else
  return exp2f(x);
#endif
}

typedef const __attribute__((address_space(1))) unsigned int* gas_u32;
typedef __attribute__((address_space(3))) unsigned int* las_u32;
__device__ __forceinline__ void gll16(const void* g, void* l) {
  __builtin_amdgcn_global_load_lds((gas_u32)g, (las_u32)l, 16, 0, 0);
}

// ---------------------------------------------------------------- prep
// cvt_w (4x512x512 fp32->bf16, 1 float4/thread) + mask_bits (4096 wave jobs)
__global__ __launch_bounds__(256) void prep(
    const float* __restrict__ w0, const float* __restrict__ w1,
    const float* __restrict__ w2, const float* __restrict__ w3,
    ushort* __restrict__ Wb,
    const int* __restrict__ mask, unsigned long long* __restrict__ MB) {
  const int tid = threadIdx.x, bid = blockIdx.x;
  int i = bid * 256 + tid;
  {
    int wsel = i >> 16, j = i & 65535;
    const float* src = (wsel == 0) ? w0 : (wsel == 1) ? w1
                     : (wsel == 2) ? w2 : w3;
    float4 vv = ((const float4*)src)[j];
    uint2 o = { cvtpk(vv.x, vv.y), cvtpk(vv.z, vv.w) };
    ((uint2*)(Wb + (size_t)wsel * 262144))[j] = o;
  }
  const int lane = tid & 63;
  const int wvg = i >> 6;
  const size_t base = (size_t)wvg * 64;
  for (int j = 0; j < 64; j += 4) {
    int v0 = mask[(base + j + 0) * 64 + lane];
    int v1 = mask[(base + j + 1) * 64 + lane];
    int v2 = mask[(base + j + 2) * 64 + lane];
    int v3 = mask[(base + j + 3) * 64 + lane];
    unsigned long long b0 = __ballot(v0 != 0), b1 = __ballot(v1 != 0);
    unsigned long long b2 = __ballot(v2 != 0), b3 = __ballot(v3 != 0);
    if (lane == 0) {
      MB[base + j] = b0; MB[base + j + 1] = b1;
      MB[base + j + 2] = b2; MB[base + j + 3] = b3;
    }
  }
}

// ---------------------------------------------------------------- QKV GEMM
// Y[8192][512] = X f32 [m][k] * W bf16 [n][k]; tile 128x128, BK=64, grid (64,4,3).
// z=0: Q, scale=0.125*log2(e); z=1: K; z=2: V transposed [b][h][hd][s].
__global__ __launch_bounds__(256, 3) void qkv_gemm(
    const float* __restrict__ q, const float* __restrict__ k,
    const float* __restrict__ v, const ushort* __restrict__ Wb,
    const float* __restrict__ bq, const float* __restrict__ bk,
    const float* __restrict__ bv, ushort* __restrict__ Qh,
    ushort* __restrict__ Kh, ushort* __restrict__ Vt) {
  __shared__ ushort SH[128 * 136];    // 34 KB: fp32 A tile [128][64] / epi buffers
  __shared__ ushort Ws[128 * 64];     // 16 KB bf16 W tile
  float* Asf = (float*)SH;
  const int z = blockIdx.z;
  const float* X = (z == 0) ? q : (z == 1) ? k : v;
  const ushort* W = Wb + (size_t)z * 262144;
  const float* bias = (z == 0) ? bq : (z == 1) ? bk : bv;
  const float scale = (z == 0) ? 0.18033688011112042f : 1.0f;
  ushort* Y = (z == 0) ? Qh : (z == 1) ? Kh : Vt;

  const int tid = threadIdx.x, wv = tid >> 6, l = tid & 63;
  const int quad = l >> 4, ln = l & 15;
  const int m0 = blockIdx.x * 128, n0 = blockIdx.y * 128;
  const int wm = (wv & 1) * 64, wn = (wv >> 1) * 64;
  const int srA = l >> 4, sA = l & 15, cA = sA >> 1, hA = sA & 1;
  const int srW = l >> 3, scW = l & 7;
  f32x4 acc[4][4] = {};

  for (int kk = 0; kk < 512; kk += 64) {
#pragma unroll
    for (int i = 0; i < 8; ++i) {      // A: 128 fp32 rows, 32/wave, 4 rows/instr
      int rowa = wv * 32 + i * 4 + srA;
      gll16(X + (size_t)(m0 + rowa) * 512 + kk + ((cA ^ (rowa & 7)) * 8 + hA * 4),
            Asf + (wv * 32 + i * 4) * 64);
    }
#pragma unroll
    for (int i = 0; i < 4; ++i) {      // W: 128 bf16 rows, 32/wave, 8 rows/instr
      int roww = wv * 32 + i * 8 + srW;
      gll16(W + (size_t)(n0 + roww) * 512 + kk + ((scW ^ (roww & 7)) * 8),
            Ws + (wv * 32 + i * 8) * 64);
    }
    __syncthreads();
#pragma unroll
    for (int ks = 0; ks < 2; ++ks) {
      bf16x8 a[4], bw[4];
#pragma unroll
      for (int mt = 0; mt < 4; ++mt) {
        int row = wm + mt * 16 + ln;
        int p = (ks * 4 + quad) ^ (row & 7);
        const float* ap = &Asf[row * 64 + p * 8];
        f32x4 x0 = *(const f32x4*)ap;
        f32x4 x1 = *(const f32x4*)(ap + 4);
        union { uint u[4]; bf16x8 v; } t;
        t.u[0] = cvtpk(x0[0], x0[1]);
        t.u[1] = cvtpk(x0[2], x0[3]);
        t.u[2] = cvtpk(x1[0], x1[1]);
        t.u[3] = cvtpk(x1[2], x1[3]);
        a[mt] = t.v;
      }
#pragma unroll
      for (int nt = 0; nt < 4; ++nt) {
        int row = wn + nt * 16 + ln;
        bw[nt] = *(const bf16x8*)&Ws[row * 64 + (((ks * 4 + quad) ^ (row & 7)) * 8)];
      }
#pragma unroll
      for (int mt = 0; mt < 4; ++mt)
#pragma unroll
        for (int nt = 0; nt < 4; ++nt)
          acc[mt][nt] = MFMA16(a[mt], bw[nt], acc[mt][nt]);
    }
    __syncthreads();
  }
  float bval[4];
#pragma unroll
  for (int nt = 0; nt < 4; ++nt) bval[nt] = bias[n0 + wn + nt * 16 + ln];

  if (z == 2) {
    // transpose via LDS: T[128 n][128 m] ushort, xor-swizzled chunks
    ushort* uT = SH;
#pragma unroll
    for (int nt = 0; nt < 4; ++nt) {
      int row = wn + nt * 16 + ln;
#pragma unroll
      for (int mt = 0; mt < 4; ++mt) {
        int mbase = wm + mt * 16 + quad * 4;
        uint2 pk = { cvtpk(acc[mt][nt][0] + bval[nt], acc[mt][nt][1] + bval[nt]),
                     cvtpk(acc[mt][nt][2] + bval[nt], acc[mt][nt][3] + bval[nt]) };
        int c = (mbase >> 3) ^ (row & 7);
        *(uint2*)&uT[row * 128 + c * 8 + (quad & 1) * 4] = pk;
      }
    }
    __syncthreads();
#pragma unroll
    for (int j = 0; j < 8; ++j) {
      int i = tid + j * 256;             // 128 rows x 16 chunks
      int row = i >> 4, cs = i & 15;
      int g = cs ^ (row & 7);
      uint4 d = *(const uint4*)&uT[row * 128 + cs * 8];
      int n = n0 + row, m = m0 + g * 8;
      int bb = m >> 11, s = m & 2047, h = n >> 6, hd = n & 63;
      *(uint4*)(Y + ((size_t)((bb * 8 + h) * 64 + hd)) * 2048 + s) = d;
    }
  } else {
    // EPI0: LDS [m 128][n 136] round-trip -> vectorized head-split stores
    ushort* uM = SH;
#pragma unroll
    for (int mt = 0; mt < 4; ++mt)
#pragma unroll
      for (int nt = 0; nt < 4; ++nt) {
        int n = wn + nt * 16 + ln;
#pragma unroll
        for (int r = 0; r < 4; ++r) {
          int m = wm + mt * 16 + quad * 4 + r;
          uM[m * 136 + n] = f2bf((acc[mt][nt][r] + bval[nt]) * scale);
        }
      }
    __syncthreads();
#pragma unroll
    for (int j = 0; j < 8; ++j) {
      int i = tid + j * 256;             // 128 rows x 16 chunks of 8
      int row = i >> 4, cs = i & 15;
      uint4 d = *(const uint4*)&uM[row * 136 + cs * 8];
      int m = m0 + row, n = n0 + cs * 8;
      int bb = m >> 11, s = m & 2047, h = n >> 6, hd = n & 63;
      *(uint4*)(Y + (((size_t)(bb * 8 + h) * 2048) + s) * 64 + hd) = d;
    }
  }
}

// ---------------------------------------------------------------- attention
// 512 threads, 8 waves (4 qh x 2 kvh), 128 q-rows/block: each K/V tile staged
// once per 128 q-rows (half the staging of the 64-row version). Per-wave math
// identical to r2 (32x32x16, S^T=K.Q^T, cvt_pk, permlane32_swap, ones-MFMA l).
__global__ __launch_bounds__(512, 4) void attn(
    const ushort* __restrict__ Qh, const ushort* __restrict__ Kh,
    const ushort* __restrict__ Vt, const unsigned long long* __restrict__ MB,
    ushort* __restrict__ O) {
  __shared__ ushort SMEM[16384];          // Ks 16KB | Vs 16KB (reused at end)
  ushort* Ks = SMEM;                      // [kv 128][d 64], chunk-swizzled
  ushort* Vs = SMEM + 8192;               // [hd 64][kv 128], chunk-swizzled
  const int tid = threadIdx.x, wv = tid >> 6, lane = tid & 63;
  const int hs = lane >> 5, lq = lane & 31;
  const int qh = wv >> 1, kvh = wv & 1;   // qh 0..3
  const int bh = blockIdx.x, qb = blockIdx.y;
  const size_t hoff = (size_t)bh * 2048 * 64;
  const int q0 = qb * 128;
  const int qg = q0 + qh * 32 + lq;
  const int srK = lane >> 3, scK = lane & 7;
  const int srV = lane >> 4, scV = lane & 15;

  bf16x8 qf[4];                            // B-frag: k = 16*ki + 8*hs + j
#pragma unroll
  for (int ki = 0; ki < 4; ++ki)
    qf[ki] = *(const bf16x8*)(Qh + hoff + (size_t)qg * 64 + ki * 16 + hs * 8);

  bf16x8 ones;
#pragma unroll
  for (int j = 0; j < 8; ++j) ones[j] = (__bf16)1.0f;

  f32x16 po0 = {}, po1 = {};               // O^T accum, col=q
  f32x16 lacc = {};                        // row-sum accum (all regs equal)
  const unsigned long long* mrow = MB + ((size_t)(bh >> 3) * 2048 + qg) * 32;

  for (int it = 0; it < 16; ++it) {
    const int kv0 = it * 128;
#pragma unroll
    for (int i = 0; i < 2; ++i) {          // K: 128 rows/8 waves; V: 64 rows
      int row = wv * 16 + i * 8 + srK;
      gll16(Kh + hoff + (size_t)(kv0 + row) * 64 + ((scK ^ (row & 7)) * 8),
            Ks + (wv * 16 + i * 8) * 64);
      int rv = wv * 8 + i * 4 + srV;
      gll16(Vt + hoff + (size_t)rv * 2048 + kv0 + ((scV ^ (rv & 7)) * 8),
            Vs + (wv * 8 + i * 4) * 128);
    }
    unsigned long long mbw = mrow[it * 2 + kvh];
    __syncthreads();

#pragma unroll
    for (int ch = 0; ch < 2; ++ch) {
      const int kvb = kvh * 64 + ch * 32;
      f32x16 sc_ = {};
#pragma unroll
      for (int ki = 0; ki < 4; ++ki) {
        int row = kvb + lq;
        bf16x8 ak = *(const bf16x8*)&Ks[row * 64 + (((2 * ki + hs) ^ (row & 7)) * 8)];
        sc_ = MFMA32(ak, qf[ki], sc_);
      }
      uint pk[8];
#pragma unroll
      for (int c = 0; c < 4; ++c) {
        unsigned nib = (unsigned)(mbw >> (ch * 32 + c * 8 + hs * 4)) & 0xFu;
        float p0 = (nib & 1u) ? exp2r(sc_[4 * c + 0]) : 0.f;
        float p1 = (nib & 2u) ? exp2r(sc_[4 * c + 1]) : 0.f;
        float p2 = (nib & 4u) ? exp2r(sc_[4 * c + 2]) : 0.f;
        float p3 = (nib & 8u) ? exp2r(sc_[4 * c + 3]) : 0.f;
        pk[2 * c + 0] = cvtpk(p0, p1);
        pk[2 * c + 1] = cvtpk(p2, p3);
      }
#pragma unroll
      for (int t2 = 0; t2 < 2; ++t2) {
        union { uint u[4]; bf16x8 v; } bp;
#if __has_builtin(__builtin_amdgcn_permlane32_swap)
        uint32x2 r02 = __builtin_amdgcn_permlane32_swap(pk[4 * t2 + 0], pk[4 * t2 + 2], false, false);
        uint32x2 r13 = __builtin_amdgcn_permlane32_swap(pk[4 * t2 + 1], pk[4 * t2 + 3], false, false);
        bp.u[0] = r02[0];
        bp.u[1] = r13[0];
        bp.u[2] = r02[1];
        bp.u[3] = r13[1];
#else
        uint bx0 = (uint)__shfl_xor((int)(hs ? pk[4 * t2 + 0] : pk[4 * t2 + 2]), 32);
        uint bx1 = (uint)__shfl_xor((int)(hs ? pk[4 * t2 + 1] : pk[4 * t2 + 3]), 32);
        bp.u[0] = hs ? bx0 : pk[4 * t2 + 0];
        bp.u[1] = hs ? bx1 : pk[4 * t2 + 1];
        bp.u[2] = hs ? pk[4 * t2 + 2] : bx0;
        bp.u[3] = hs ? pk[4 * t2 + 3] : bx1;
#endif
        lacc = MFMA32(ones, bp.v, lacc);   // row-sum of P, col=q
#pragma unroll
        for (int m2 = 0; m2 < 2; ++m2) {
          int hd = m2 * 32 + lq;
          int gch = (kvb >> 3) + 2 * t2 + hs;
          bf16x8 av = *(const bf16x8*)&Vs[hd * 128 + ((gch ^ (hd & 7)) * 8)];
          if (m2 == 0) po0 = MFMA32(av, bp.v, po0);
          else         po1 = MFMA32(av, bp.v, po1);
        }
      }
    }
    __syncthreads();
  }

  // epilogue in two 64-row passes (qh pairs {0,1} then {2,3}) in 32KB LDS
  float l_own = lacc[0];                   // full sum over this wave's kv half
  float* psh = (float*)Ks;                 // [64 q][64 hd] f32
  float* lsh = (float*)Vs;                 // [qp][64]
  ushort* Osh = Vs + 256;                  // [64 q][72]
  const int qp = qh & 1;
#pragma unroll
  for (int p = 0; p < 2; ++p) {
    if ((qh >> 1) == p && kvh == 1) {
#pragma unroll
      for (int i = 0; i < 16; ++i) psh[(qp * 32 + i) * 64 + lane] = po0[i];
#pragma unroll
      for (int i = 0; i < 16; ++i) psh[(qp * 32 + 16 + i) * 64 + lane] = po1[i];
      lsh[qp * 64 + lane] = l_own;
    }
    __syncthreads();
    if ((qh >> 1) == p && kvh == 0) {
      float linv = 1.0f / (l_own + lsh[qp * 64 + lane]);
      int row = qp * 32 + lq;
#pragma unroll
      for (int m2 = 0; m2 < 2; ++m2) {
#pragma unroll
        for (int c = 0; c < 4; ++c)
#pragma unroll
          for (int b2 = 0; b2 < 2; ++b2) {
            int r = 4 * c + 2 * b2;
            float v0, v1;
            if (m2 == 0) {
              v0 = (po0[r] + psh[(qp * 32 + r) * 64 + lane]) * linv;
              v1 = (po0[r + 1] + psh[(qp * 32 + r + 1) * 64 + lane]) * linv;
            } else {
              v0 = (po1[r] + psh[(qp * 32 + 16 + r) * 64 + lane]) * linv;
              v1 = (po1[r + 1] + psh[(qp * 32 + 16 + r + 1) * 64 + lane]) * linv;
            }
            int hd = m2 * 32 + 8 * c + 4 * hs + 2 * b2;
            *(uint*)&Osh[row * 72 + hd] = cvtpk(v0, v1);
          }
      }
    }
    __syncthreads();
    {
      int i = tid;                         // 64 rows x 8 chunks = 512 uint4
      int row = i >> 3, cc = i & 7;
      uint4 d = *(const uint4*)&Osh[row * 72 + cc * 8];
      *(uint4*)(O + ((size_t)((bh >> 3) * 2048 + q0 + p * 64 + row)) * 512 +
                (bh & 7) * 64 + cc * 8) = d;
    }
    __syncthreads();
  }
}

// ---------------------------------------------------------------- out proj
__global__ __launch_bounds__(256) void out_gemm(
    const ushort* __restrict__ X, const ushort* __restrict__ W,
    const float* __restrict__ bias, float* __restrict__ Y) {
  __shared__ ushort As[64 * 64];
  __shared__ ushort Ws[128 * 64];
  const int tid = threadIdx.x, wv = tid >> 6, l = tid & 63;
  const int quad = l >> 4, ln = l & 15;
  const int m0 = blockIdx.x * 64, n0 = blockIdx.y * 128;
  const int wm = (wv & 1) * 32, wn = (wv >> 1) * 64;
  const int sr = l >> 3, sc = l & 7;
  f32x4 acc[2][4] = {};
  for (int kk = 0; kk < 512; kk += 64) {
#pragma unroll
    for (int i = 0; i < 2; ++i) {
      int row = wv * 16 + i * 8 + sr;
      gll16(X + (size_t)(m0 + row) * 512 + kk + ((sc ^ (row & 7)) * 8),
            As + (wv * 16 + i * 8) * 64);
    }
#pragma unroll
    for (int i = 0; i < 4; ++i) {
      int row = wv * 32 + i * 8 + sr;
      gll16(W + (size_t)(n0 + row) * 512 + kk + ((sc ^ (row & 7)) * 8),
            Ws + (wv * 32 + i * 8) * 64);
    }
    __syncthreads();
#pragma unroll
    for (int ks = 0; ks < 2; ++ks) {
      bf16x8 a[2], bw[4];
#pragma unroll
      for (int mt = 0; mt < 2; ++mt) {
        int row = wm + mt * 16 + ln;
        a[mt] = *(const bf16x8*)&As[row * 64 + (((ks * 4 + quad) ^ (row & 7)) * 8)];
      }
#pragma unroll
      for (int nt = 0; nt < 4; ++nt) {
        int row = wn + nt * 16 + ln;
        bw[nt] = *(const bf16x8*)&Ws[row * 64 + (((ks * 4 + quad) ^ (row & 7)) * 8)];
      }
#pragma unroll
      for (int mt = 0; mt < 2; ++mt)
#pragma unroll
        for (int nt = 0; nt < 4; ++nt)
          acc[mt][nt] = MFMA16(a[mt], bw[nt], acc[mt][nt]);
    }
    __syncthreads();
  }
#pragma unroll
  for (int mt = 0; mt < 2; ++mt)
#pragma unroll
    for (int nt = 0; nt < 4; ++nt) {
      int n = n0 + wn + nt * 16 + ln;
      float bval = bias[n];
#pragma unroll
      for (int r = 0; r < 4; ++r) {
        int m = m0 + wm + mt * 16 + quad * 4 + r;
        Y[(size_t)m * 512 + n] = acc[mt][nt][r] + bval;
      }
    }
}

// ---------------------------------------------------------------- launch
extern "C" void kernel_launch(void* const* d_in, const int* in_sizes, int n_in,
                              void* d_out, int out_size, void* d_ws, size_t ws_size,
                              hipStream_t stream) {
  const float* q    = (const float*)d_in[0];
  const float* k    = (const float*)d_in[1];
  const float* v    = (const float*)d_in[2];
  const int*   mask = (const int*)d_in[3];
  const float* Wq   = (const float*)d_in[4];
  const float* bq   = (const float*)d_in[5];
  const float* Wk   = (const float*)d_in[6];
  const float* bk   = (const float*)d_in[7];
  const float* Wv   = (const float*)d_in[8];
  const float* bv   = (const float*)d_in[9];
  const float* Wo   = (const float*)d_in[10];
  const float* bo   = (const float*)d_in[11];
  float* out = (float*)d_out;

  uint8_t* ws = (uint8_t*)d_ws;
  const size_t MiB = 1u << 20;
  ushort* Oh = (ushort*)(ws + 0 * MiB);
  ushort* Qh = (ushort*)(ws + 8 * MiB);
  ushort* Kh = (ushort*)(ws + 16 * MiB);
  ushort* Vt = (ushort*)(ws + 24 * MiB);
  unsigned long long* MB = (unsigned long long*)(ws + 32 * MiB);
  ushort* Wb = (ushort*)(ws + 34 * MiB);

  prep<<<1024, 256, 0, stream>>>(Wq, Wk, Wv, Wo, Wb, mask, MB);
  qkv_gemm<<<dim3(64, 4, 3), 256, 0, stream>>>(q, k, v, Wb, bq, bk, bv, Qh, Kh, Vt);
  attn<<<dim3(32, 16), 512, 0, stream>>>(Qh, Kh, Vt, MB, Oh);
  out_gemm<<<dim3(128, 4), 256, 0, stream>>>(Oh, Wb + 3 * 262144, bo, out);
}